// Round 10
// baseline (259.753 us; speedup 1.0000x reference)
//
#include <hip/hip_runtime.h>
#include <hip/hip_bf16.h>

typedef _Float16 f16;
typedef _Float16 f16x4 __attribute__((ext_vector_type(4)));
typedef _Float16 f16x8 __attribute__((ext_vector_type(8)));
typedef float f32x4 __attribute__((ext_vector_type(4)));

#define S_LEN 4096
#define DIM   512
#define NH    8
#define DH    64
#define BATCH 2
#define BHDIM (BATCH*NH)   // 16

// Q pre-scale: 1/sqrt(64) * log2(e)  (softmax done in exp2 domain)
#define QSCALE 0.18033688011112042f

// NOTE: legacy K=16 MFMA builtin has NO underscore before f16 (pre-gfx950 naming);
// the gfx950-new K=32 ones (16x16x32_f16) DO. Verified by compiler note in r9.
#define MFMA16(a,b,c) __builtin_amdgcn_mfma_f32_16x16x16f16(a,b,c,0,0,0)

__device__ __forceinline__ void gld16(const f16* g, f16* l) {
#if __has_builtin(__builtin_amdgcn_global_load_lds)
  __builtin_amdgcn_global_load_lds((const __attribute__((address_space(1))) void*)g,
                                   (__attribute__((address_space(3))) void*)l, 16, 0, 0);
#else
  *(f16x8*)l = *(const f16x8*)g;
#endif
}

// ---------------- Fused prep: rmsnorm + weight transpose + rope tables ----------------
__global__ __launch_bounds__(256) void prep_kernel(
    const float* __restrict__ x, const float* __restrict__ scale,
    const float* __restrict__ Wq, const float* __restrict__ Wk,
    const float* __restrict__ Wv, const float* __restrict__ Wo,
    f16* __restrict__ xn, f16* __restrict__ wt_qkv, f16* __restrict__ wo_t,
    float* __restrict__ ctab, float* __restrict__ stab) {
  int blk = blockIdx.x;
  int tid = threadIdx.x;
  if (blk < 8192) {                       // RMSNorm row
    int row = blk;
    const float* xr = x + (size_t)row * DIM;
    float2 v = *(const float2*)(xr + tid*2);
    float ss = v.x*v.x + v.y*v.y;
    #pragma unroll
    for (int off = 32; off > 0; off >>= 1) ss += __shfl_down(ss, off);
    __shared__ float red[4];
    if ((tid & 63) == 0) red[tid >> 6] = ss;
    __syncthreads();
    float tot = red[0] + red[1] + red[2] + red[3];
    float inv = rsqrtf(tot * (1.0f/DIM) + 1e-6f);
    float2 s = *(const float2*)(scale + tid*2);
    xn[(size_t)row*DIM + tid*2+0] = (f16)(v.x*inv*s.x);
    xn[(size_t)row*DIM + tid*2+1] = (f16)(v.y*inv*s.y);
  } else if (blk < 8192 + 1024) {         // transpose 32x32 tile
    int id = blk - 8192;
    int bx = id & 15, by = (id >> 4) & 15, mat = id >> 8;
    __shared__ f16 tile[32][33];
    const float* src = (mat == 0) ? Wq : (mat == 1) ? Wk : (mat == 2) ? Wv : Wo;
    f16* dst = (mat < 3) ? (wt_qkv + (size_t)mat*DIM*DIM) : wo_t;
    int k0 = by * 32, n0 = bx * 32;
    int tx = tid & 31, ty = tid >> 5;     // (32, 8)
    #pragma unroll
    for (int i = 0; i < 32; i += 8)
      tile[ty+i][tx] = (f16)src[(size_t)(k0+ty+i)*DIM + n0+tx];
    __syncthreads();
    #pragma unroll
    for (int i = 0; i < 32; i += 8)
      dst[(size_t)(n0+ty+i)*DIM + k0+tx] = tile[tx][ty+i];
  } else {                                // rope tables
    int idx = (blk - 9216)*256 + tid;     // 0..131071
    int t = idx >> 5, d = idx & 31;
    float theta = exp2f(-(float)d * (19.931568569324174f / 32.0f));
    float sv, cv;
    sincosf((float)t * theta, &sv, &cv);
    ctab[idx] = cv; stab[idx] = sv;
  }
}

// ------------- m97-style 128x128 GEMM core: C = A[M,512] * Bt[N,512]^T -------------
__device__ __forceinline__ void gemm128_acc(
    const f16* __restrict__ A, const f16* __restrict__ Bt,
    int m0, int n0, f16* As, f16* Bs, f32x4 (&acc)[4][4]) {
  const int tid = threadIdx.x;
  const int wave = tid >> 6, lane = tid & 63;
  const int l16 = lane & 15, quad = lane >> 4;
  const int mrow = (wave & 1) * 64, ncol = (wave >> 1) * 64;
  const int srow = tid >> 3;                    // 0..31
  const int gc = (tid & 7) ^ ((tid >> 3) & 7);  // swizzled source chunk

  for (int k0 = 0; k0 < DIM; k0 += 64) {
    if (k0) __syncthreads();
    #pragma unroll
    for (int i = 0; i < 4; i++) {
      gld16(A  + (size_t)(m0 + i*32 + srow)*DIM + k0 + gc*8, As + i*2048 + tid*8);
      gld16(Bt + (size_t)(n0 + i*32 + srow)*DIM + k0 + gc*8, Bs + i*2048 + tid*8);
    }
    __syncthreads();
    #pragma unroll
    for (int kc = 0; kc < 2; kc++) {
      f16x8 a[4], b[4];
      #pragma unroll
      for (int mt = 0; mt < 4; mt++) {
        int row = mrow + mt*16 + l16;
        a[mt] = *(const f16x8*)(As + row*64 + (((quad + 4*kc) ^ (l16 & 7)) * 8));
      }
      #pragma unroll
      for (int nt = 0; nt < 4; nt++) {
        int row = ncol + nt*16 + l16;
        b[nt] = *(const f16x8*)(Bs + row*64 + (((quad + 4*kc) ^ (l16 & 7)) * 8));
      }
      #pragma unroll
      for (int mt = 0; mt < 4; mt++)
        #pragma unroll
        for (int nt = 0; nt < 4; nt++)
          acc[mt][nt] = __builtin_amdgcn_mfma_f32_16x16x32_f16(a[mt], b[nt], acc[mt][nt], 0, 0, 0);
    }
  }
}

// ------------- QKV GEMM + table-RoPE + Q prescale -------------
__global__ __launch_bounds__(256) void qkv_gemm_kernel(
    const f16* __restrict__ xn, const f16* __restrict__ wt,
    const float* __restrict__ ctab, const float* __restrict__ stab,
    f16* __restrict__ qbuf, f16* __restrict__ kbuf, f16* __restrict__ vt) {
  __shared__ __align__(16) f16 As[128*64], Bs[128*64];
  int m0 = blockIdx.x * 128, n0 = blockIdx.y * 128;
  f32x4 acc[4][4] = {};
  gemm128_acc(xn, wt, m0, n0, As, Bs, acc);

  const int tid = threadIdx.x;
  const int wave = tid >> 6, lane = tid & 63;
  const int l16 = lane & 15, quad = lane >> 4;
  int ncol = n0 + (wave >> 1) * 64;      // head-aligned
  int which = ncol >> 9;                 // 0=q 1=k 2=v (wave-uniform)
  int head = (ncol >> 6) & 7;
  int mbase = m0 + (wave & 1) * 64;

  if (which <= 1) {                      // fused RoPE from tables
    #pragma unroll
    for (int mt = 0; mt < 4; mt++)
      #pragma unroll
      for (int nt = 0; nt < 2; nt++) {
        int d = nt*16 + l16;
        #pragma unroll
        for (int r = 0; r < 4; r++) {
          int t = (mbase + mt*16 + quad*4 + r) & 4095;
          float cv = ctab[t*32 + d], sv = stab[t*32 + d];
          float x1 = acc[mt][nt][r], x2 = acc[mt][nt+2][r];
          acc[mt][nt][r]   = x1*cv - x2*sv;
          acc[mt][nt+2][r] = x1*sv + x2*cv;
        }
      }
  }
  if (which < 2) {
    float osc = (which == 0) ? QSCALE : 1.0f;
    f16* dst = which ? kbuf : qbuf;
    #pragma unroll
    for (int mt = 0; mt < 4; mt++)
      #pragma unroll
      for (int nt = 0; nt < 4; nt++)
        #pragma unroll
        for (int r = 0; r < 4; r++) {
          int m = mbase + mt*16 + quad*4 + r;
          int b = m >> 12, t = m & 4095;
          dst[(((size_t)(b*NH + head))*S_LEN + t)*DH + nt*16 + l16] = (f16)(acc[mt][nt][r]*osc);
        }
  } else {                               // V transposed, pack 4 consecutive tokens
    #pragma unroll
    for (int mt = 0; mt < 4; mt++)
      #pragma unroll
      for (int nt = 0; nt < 4; nt++) {
        int m = mbase + mt*16 + quad*4;
        int b = m >> 12, t = m & 4095;
        int d = nt*16 + l16;
        f16x4 v4 = {(f16)acc[mt][nt][0], (f16)acc[mt][nt][1],
                    (f16)acc[mt][nt][2], (f16)acc[mt][nt][3]};
        *(f16x4*)(vt + ((size_t)((b*NH + head)*DH + d))*S_LEN + t) = v4;
      }
  }
}

// ------------- Flash attention (causal), 128 q-rows/block, 128-key tiles, KV-split -------------
// S^T softmax (per-lane state), PV via 16x16x16 MFMA: P stays in registers (S^T C-layout
// == 16x16x16 B-frag layout, k=quad*4+r). O accumulated TRANSPOSED (col = qrow = l16).
#define VSW 140   // vs row stride in f16 (70 words: 6*l16 bank rotation, b64-aligned)
__global__ __launch_bounds__(256, 3) void attn_kernel(
    const f16* __restrict__ qbuf, const f16* __restrict__ kbuf,
    const f16* __restrict__ vtb, f16* __restrict__ ao,
    f16* __restrict__ opart, float* __restrict__ mlb, int nsplit) {
  int bx = blockIdx.x;
  int u = bx / nsplit;
  int s = bx - u*nsplit;
  int qtb = 31 - (u >> 4);               // heavy q-tiles dispatch first
  int bh = u & 15;
  int ntiles = qtb + 1;
  int ts = (s * ntiles) / nsplit;
  int te = ((s+1) * ntiles) / nsplit;
  if (ts >= te) return;
  bool full = (te - ts) == ntiles;

  int tid = threadIdx.x;
  int wave = tid >> 6, lane = tid & 63;
  int l16 = lane & 15, quad = lane >> 4;

  const f16* Q = qbuf + (size_t)bh*S_LEN*DH;
  const f16* K = kbuf + (size_t)bh*S_LEN*DH;
  const f16* V = vtb  + (size_t)bh*DH*S_LEN;   // [dh][s]

  int rw = qtb*128 + wave*32;

  f16x8 qa[2][2];
  #pragma unroll
  for (int mf = 0; mf < 2; mf++) {
    const f16* qrow = Q + (size_t)(rw + mf*16 + l16)*DH + quad*8;
    qa[mf][0] = *(const f16x8*)(qrow);
    qa[mf][1] = *(const f16x8*)(qrow + 32);
  }

  f32x4 o[2][4] = {};                    // O^T: [mf][dnt]: row=dh(quad*4+r), col=qrow(l16)
  float m_i[2] = {-1e30f, -1e30f};       // per-lane (qrow = l16), replicated over quads
  float l_i[2] = {0.f, 0.f};

  __shared__ __align__(16) f16 kt[128*64];   // [kv][dh], xor-16B-chunk swizzle
  __shared__ __align__(16) f16 vs[64*VSW];   // [dh][kv], padded stride

  // staging maps
  int krow = tid >> 1, kc0 = (tid & 1) * 4;  // K: 128 rows x 8 chunks
  int vrow = tid >> 2, vc = tid & 3;         // V: 64 rows x 16 chunks

  {                                          // prologue: stage tile ts
    int kv0 = ts * 128;
    #pragma unroll
    for (int i = 0; i < 4; i++) {
      *(f16x8*)(kt + krow*64 + (((kc0+i) ^ (krow & 7))*8)) =
          *(const f16x8*)(K + (size_t)(kv0 + krow)*DH + (kc0+i)*8);
      *(f16x8*)(vs + vrow*VSW + (4*i + vc)*8) =
          *(const f16x8*)(V + (size_t)vrow*S_LEN + kv0 + (4*i + vc)*8);
    }
  }
  __syncthreads();

  for (int it = ts; it < te; ++it) {
    int kv0 = it * 128;
    bool have_next = (it + 1 < te);
    f16x8 pk[4], pv[4];
    if (have_next) {
      int kvn = kv0 + 128;
      #pragma unroll
      for (int i = 0; i < 4; i++) {
        pk[i] = *(const f16x8*)(K + (size_t)(kvn + krow)*DH + (kc0+i)*8);
        pv[i] = *(const f16x8*)(V + (size_t)vrow*S_LEN + kvn + (4*i + vc)*8);
      }
    }

    // ---- S^T = K Q^T : C-layout row=key_local(quad*4+r + 16nt), col=qrow(l16) ----
    f32x4 st[2][8];
    #pragma unroll
    for (int nt = 0; nt < 8; nt++) {
      int row = nt*16 + l16;
      f16x8 kf0 = *(const f16x8*)(kt + row*64 + (((quad)     ^ (row & 7))*8));
      f16x8 kf1 = *(const f16x8*)(kt + row*64 + (((quad + 4) ^ (row & 7))*8));
      f32x4 z0 = {}, z1 = {};
      z0 = __builtin_amdgcn_mfma_f32_16x16x32_f16(kf0, qa[0][0], z0, 0, 0, 0);
      z1 = __builtin_amdgcn_mfma_f32_16x16x32_f16(kf0, qa[1][0], z1, 0, 0, 0);
      st[0][nt] = __builtin_amdgcn_mfma_f32_16x16x32_f16(kf1, qa[0][1], z0, 0, 0, 0);
      st[1][nt] = __builtin_amdgcn_mfma_f32_16x16x32_f16(kf1, qa[1][1], z1, 0, 0, 0);
    }

    bool last = (it == ntiles - 1);
    f16x4 p16[2][8];
    #pragma unroll
    for (int mf = 0; mf < 2; mf++) {
      int qrow = rw + mf*16 + l16;
      float rmx = -1e30f;
      if (last) {                        // diagonal tile: causal mask
        #pragma unroll
        for (int nt = 0; nt < 8; nt++) {
          int kbase = kv0 + nt*16 + quad*4;
          #pragma unroll
          for (int r = 0; r < 4; r++) {
            float v = st[mf][nt][r];
            if (kbase + r > qrow) v = -1e30f;
            st[mf][nt][r] = v;
            rmx = fmaxf(rmx, v);
          }
        }
      } else {
        #pragma unroll
        for (int nt = 0; nt < 8; nt++)
          #pragma unroll
          for (int r = 0; r < 4; r++) rmx = fmaxf(rmx, st[mf][nt][r]);
      }
      rmx = fmaxf(rmx, __shfl_xor(rmx, 16));
      rmx = fmaxf(rmx, __shfl_xor(rmx, 32));
      float mnew = fmaxf(m_i[mf], rmx);
      float alpha = exp2f(m_i[mf] - mnew);
      m_i[mf] = mnew;
      #pragma unroll
      for (int dnt = 0; dnt < 4; dnt++)      // per-lane alpha (O^T col = l16 = qrow)
        #pragma unroll
        for (int r = 0; r < 4; r++) o[mf][dnt][r] *= alpha;
      float rs = 0.f;
      #pragma unroll
      for (int nt = 0; nt < 8; nt++)
        #pragma unroll
        for (int r = 0; r < 4; r++) {
          float p = exp2f(st[mf][nt][r] - mnew);
          rs += p;
          p16[mf][nt][r] = (f16)p;
        }
      rs += __shfl_xor(rs, 16);
      rs += __shfl_xor(rs, 32);
      l_i[mf] = l_i[mf]*alpha + rs;
    }

    // ---- O^T += V^T P^T : A = V^T frag (k=quad*4+j), B = p16 (S^T C-layout) ----
    #pragma unroll
    for (int dnt = 0; dnt < 4; dnt++) {
      const f16* vbase = vs + (dnt*16 + l16)*VSW;
      #pragma unroll
      for (int nt = 0; nt < 8; nt++) {
        f16x4 va = *(const f16x4*)(vbase + nt*16 + quad*4);
        o[0][dnt] = MFMA16(va, p16[0][nt], o[0][dnt]);
        o[1][dnt] = MFMA16(va, p16[1][nt], o[1][dnt]);
      }
    }

    __syncthreads();                     // readers done with current tile
    if (have_next) {
      #pragma unroll
      for (int i = 0; i < 4; i++) {
        *(f16x8*)(kt + krow*64 + (((kc0+i) ^ (krow & 7))*8)) = pk[i];
        *(f16x8*)(vs + vrow*VSW + (4*i + vc)*8) = pv[i];
      }
    }
    __syncthreads();                     // writes visible
  }

  // epilogue
  int b = bh >> 3, h = bh & 7;
  if (full) {
    #pragma unroll
    for (int mf = 0; mf < 2; mf++) {
      float invl = 1.0f / l_i[mf];
      int qrow = rw + mf*16 + l16;
      size_t base = ((size_t)(b*S_LEN + qrow))*DIM + h*DH;
      #pragma unroll
      for (int dnt = 0; dnt < 4; dnt++) {
        f16x4 w = {(f16)(o[mf][dnt][0]*invl), (f16)(o[mf][dnt][1]*invl),
                   (f16)(o[mf][dnt][2]*invl), (f16)(o[mf][dnt][3]*invl)};
        *(f16x4*)(ao + base + dnt*16 + quad*4) = w;
      }
    }
  } else {
    #pragma unroll
    for (int mf = 0; mf < 2; mf++) {
      int qrl = wave*32 + mf*16 + l16;
      size_t pb = ((size_t)(u*4 + s)*128 + qrl)*64;
      #pragma unroll
      for (int dnt = 0; dnt < 4; dnt++) {
        f16x4 w = {(f16)o[mf][dnt][0], (f16)o[mf][dnt][1],
                   (f16)o[mf][dnt][2], (f16)o[mf][dnt][3]};
        *(f16x4*)(opart + pb + dnt*16 + quad*4) = w;
      }
      if (quad == 0) {
        mlb[(size_t)(u*4 + s)*256 + qrl] = m_i[mf];
        mlb[(size_t)(u*4 + s)*256 + 128 + qrl] = l_i[mf];
      }
    }
  }
}

// ------------- Combine KV-split partials -------------
__global__ __launch_bounds__(256) void combine_kernel(
    const f16* __restrict__ opart, const float* __restrict__ mlb,
    f16* __restrict__ ao) {
  int u = blockIdx.x;
  int qtb = 31 - (u >> 4);
  int bh = u & 15;
  int ntiles = qtb + 1;
  int tid = threadIdx.x;
  int qrow = tid >> 1;
  int dh0 = (tid & 1) * 32;
  float ms[4]; bool v[4]; int valid = 0; float mmax = -1e30f;
  #pragma unroll
  for (int s = 0; s < 4; s++) {
    int t0 = (s*ntiles) >> 2, t1 = ((s+1)*ntiles) >> 2;
    v[s] = t1 > t0;
    if (v[s]) { ms[s] = mlb[(size_t)(u*4+s)*256 + qrow]; mmax = fmaxf(mmax, ms[s]); valid++; }
  }
  if (valid <= 1) return;                // single full split wrote ao directly
  float acc[32] = {};
  float lsum = 0.f;
  #pragma unroll
  for (int s = 0; s < 4; s++) if (v[s]) {
    float w = exp2f(ms[s] - mmax);
    lsum += w * mlb[(size_t)(u*4+s)*256 + 128 + qrow];
    const f16* op = opart + ((size_t)(u*4+s)*128 + qrow)*64 + dh0;
    #pragma unroll
    for (int j = 0; j < 32; j++) acc[j] += w * (float)op[j];
  }
  float inv = 1.f/lsum;
  int b = bh >> 3, h = bh & 7;
  f16* dst = ao + ((size_t)(b*S_LEN + qtb*128 + qrow))*DIM + h*DH + dh0;
  #pragma unroll
  for (int j = 0; j < 32; j++) dst[j] = (f16)(acc[j]*inv);
}

// ------------- Output GEMM: ao[8192,512] @ Wo -> out f32 -------------
__global__ __launch_bounds__(256) void out_gemm_kernel(
    const f16* __restrict__ ao, const f16* __restrict__ wot,
    float* __restrict__ out) {
  __shared__ __align__(16) f16 As[128*64], Bs[128*64];
  int m0 = blockIdx.x * 128, n0 = blockIdx.y * 128;
  f32x4 acc[4][4] = {};
  gemm128_acc(ao, wot, m0, n0, As, Bs, acc);

  const int tid = threadIdx.x;
  const int wave = tid >> 6, lane = tid & 63;
  const int l16 = lane & 15, quad = lane >> 4;
  int ncol = n0 + (wave >> 1) * 64;
  int mbase = m0 + (wave & 1) * 64;
  #pragma unroll
  for (int mt = 0; mt < 4; mt++)
    #pragma unroll
    for (int nt = 0; nt < 4; nt++)
      #pragma unroll
      for (int r = 0; r < 4; r++)
        out[(size_t)(mbase + mt*16 + quad*4 + r)*DIM + ncol + nt*16 + l16] = acc[mt][nt][r];
}

extern "C" void kernel_launch(void* const* d_in, const int* in_sizes, int n_in,
                              void* d_out, int out_size, void* d_ws, size_t ws_size,
                              hipStream_t stream) {
  const float* x     = (const float*)d_in[0];
  const float* scale = (const float*)d_in[1];
  const float* Wq    = (const float*)d_in[2];
  const float* Wk    = (const float*)d_in[3];
  const float* Wv    = (const float*)d_in[4];
  const float* Wo    = (const float*)d_in[5];
  float* out = (float*)d_out;

  const size_t ROWS = (size_t)BATCH * S_LEN;   // 8192
  char* ws = (char*)d_ws;
  f16* xn     = (f16*)ws;  ws += ROWS * DIM * sizeof(f16);            // 8 MB (reused as ao)
  f16* wt_qkv = (f16*)ws;  ws += (size_t)3 * DIM * DIM * sizeof(f16); // 1.5 MB
  f16* wo_t   = (f16*)ws;  ws += (size_t)DIM * DIM * sizeof(f16);     // 0.5 MB
  f16* qb     = (f16*)ws;  ws += (size_t)BHDIM * S_LEN * DH * sizeof(f16); // 8 MB
  f16* kb     = (f16*)ws;  ws += (size_t)BHDIM * S_LEN * DH * sizeof(f16); // 8 MB
  f16* vt     = (f16*)ws;  ws += (size_t)BHDIM * S_LEN * DH * sizeof(f16); // 8 MB
  float* ctab = (float*)ws; ws += (size_t)S_LEN * 32 * sizeof(float);  // 0.5 MB
  float* stab = (float*)ws; ws += (size_t)S_LEN * 32 * sizeof(float);  // 0.5 MB
  size_t need_base = (size_t)(ws - (char*)d_ws);
  f16* opart  = (f16*)ws;   ws += (size_t)2048 * 128 * 64 * sizeof(f16); // 33.5 MB
  float* mlb  = (float*)ws; ws += (size_t)2048 * 256 * sizeof(float);    // 2 MB
  size_t need_split = (size_t)(ws - (char*)d_ws);
  f16* ao     = xn;  // overlay: xn dead after qkv_gemm

  if (ws_size < need_base) return;             // loud failure
  int nsplit = (ws_size >= need_split) ? 4 : 1;

  prep_kernel     <<<9728, 256, 0, stream>>>(x, scale, Wq, Wk, Wv, Wo,
                                             xn, wt_qkv, wo_t, ctab, stab);
  qkv_gemm_kernel <<<dim3(64,12), 256, 0, stream>>>(xn, wt_qkv, ctab, stab, qb, kb, vt);
  attn_kernel     <<<512*nsplit, 256, 0, stream>>>(qb, kb, vt, ao, opart, mlb, nsplit);
  if (nsplit == 4)
    combine_kernel<<<512, 256, 0, stream>>>(opart, mlb, ao);
  out_gemm_kernel <<<dim3(64,4), 256, 0, stream>>>(ao, wo_t, out);
}